// Round 2
// baseline (3105.872 us; speedup 1.0000x reference)
//
#include <hip/hip_runtime.h>

#define H 64

// ---------------------------------------------------------------------------
// Layer-1 scatter: agg[dst][f] += x[src][f].
// One thread per (edge, 4 features): a wave covers one edge's 64 features.
// Coalesced float4 gather of the src row; 4 fp32 HW atomics to the dst row.
// ---------------------------------------------------------------------------
__global__ void scatter1_kernel(const float* __restrict__ x, const int* __restrict__ ei,
                                float* __restrict__ agg, int E, int N) {
    long long t = (long long)blockIdx.x * blockDim.x + threadIdx.x;
    long long tot = (long long)E * (H / 4);
    if (t >= tot) return;
    int e = (int)(t >> 4);          // 16 threads per edge
    int f4 = (int)(t & 15);         // which float4 of the row
    int s = ei[e];
    int d = ei[E + e];
    if ((unsigned)s >= (unsigned)N || (unsigned)d >= (unsigned)N) return; // defensive
    const float4 v = *(const float4*)(x + (long long)s * H + f4 * 4);
    float* dstp = agg + (long long)d * H + f4 * 4;
    unsafeAtomicAdd(dstp + 0, v.x);
    unsafeAtomicAdd(dstp + 1, v.y);
    unsafeAtomicAdd(dstp + 2, v.z);
    unsafeAtomicAdd(dstp + 3, v.w);
}

// ---------------------------------------------------------------------------
// Layer-2 scatter: gathers pre-BN h1, applies folded BN affine, scatters.
// ---------------------------------------------------------------------------
__global__ void scatter2_kernel(const float* __restrict__ h1p, const float* __restrict__ scale,
                                const float* __restrict__ shiftv, const int* __restrict__ ei,
                                float* __restrict__ agg, int E, int N) {
    long long t = (long long)blockIdx.x * blockDim.x + threadIdx.x;
    long long tot = (long long)E * (H / 4);
    if (t >= tot) return;
    int e = (int)(t >> 4);
    int f4 = (int)(t & 15);
    int s = ei[e];
    int d = ei[E + e];
    if ((unsigned)s >= (unsigned)N || (unsigned)d >= (unsigned)N) return;
    int f = f4 * 4;
    const float4 v = *(const float4*)(h1p + (long long)s * H + f);
    float* dstp = agg + (long long)d * H + f;
    unsafeAtomicAdd(dstp + 0, v.x * scale[f + 0] + shiftv[f + 0]);
    unsafeAtomicAdd(dstp + 1, v.y * scale[f + 1] + shiftv[f + 1]);
    unsafeAtomicAdd(dstp + 2, v.z * scale[f + 2] + shiftv[f + 2]);
    unsafeAtomicAdd(dstp + 3, v.w * scale[f + 3] + shiftv[f + 3]);
}

// ---------------------------------------------------------------------------
// Thread-per-node 2-layer MLP (layer 1).  Weight indices are wave-uniform ->
// scalar (s_load) reads, L2-resident.  h/u fully unrolled -> register arrays.
// ---------------------------------------------------------------------------
__global__ __launch_bounds__(64)
void mlp1_kernel(const float* __restrict__ x, const float* __restrict__ agg,
                 const float* __restrict__ W1a, const float* __restrict__ B1a,
                 const float* __restrict__ W1b, const float* __restrict__ B1b,
                 float* __restrict__ h1p, int N) {
    int i = blockIdx.x * blockDim.x + threadIdx.x;
    if (i >= N) return;
    long long base = (long long)i * H;
    float h[H], u[H];
#pragma unroll
    for (int f = 0; f < H; ++f)
        h[f] = x[base + f] + agg[base + f];
#pragma unroll
    for (int j = 0; j < H; ++j) u[j] = B1a[j];
#pragma unroll
    for (int k = 0; k < H; ++k) {
        float hk = h[k];
#pragma unroll
        for (int j = 0; j < H; ++j) u[j] = fmaf(hk, W1a[k * H + j], u[j]);
    }
#pragma unroll
    for (int j = 0; j < H; ++j) u[j] = fmaxf(u[j], 0.f);
#pragma unroll
    for (int j = 0; j < H; ++j) h[j] = B1b[j];
#pragma unroll
    for (int k = 0; k < H; ++k) {
        float uk = u[k];
#pragma unroll
        for (int j = 0; j < H; ++j) h[j] = fmaf(uk, W1b[k * H + j], h[j]);
    }
#pragma unroll
    for (int j = 0; j < H; ++j) h1p[base + j] = h[j];
}

// ---------------------------------------------------------------------------
// Column sums + sumsq of h1p for batchnorm stats.  Wave reads rows coalesced,
// lane f owns feature f; one atomic per feature per wave.
// ---------------------------------------------------------------------------
__global__ void colsum_kernel(const float* __restrict__ h1p, float* __restrict__ stats, int N) {
    int lane = threadIdx.x & 63;
    int wave = (int)((blockIdx.x * (long long)blockDim.x + threadIdx.x) >> 6);
    int nwaves = (int)(((long long)gridDim.x * blockDim.x) >> 6);
    float s = 0.f, s2 = 0.f;
    for (int r = wave; r < N; r += nwaves) {
        float v = h1p[(long long)r * H + lane];
        s += v;
        s2 += v * v;
    }
    unsafeAtomicAdd(&stats[lane], s);
    unsafeAtomicAdd(&stats[H + lane], s2);
}

__global__ void bn_finalize_kernel(const float* __restrict__ stats,
                                   const float* __restrict__ gamma,
                                   const float* __restrict__ beta,
                                   float* __restrict__ scale, float* __restrict__ shiftv, float n) {
    int f = threadIdx.x;
    if (f >= H) return;
    float mean = stats[f] / n;
    float var = stats[H + f] / n - mean * mean;   // biased, matches jnp.var
    var = fmaxf(var, 0.f);
    float s = gamma[f] * rsqrtf(var + 1e-5f);
    scale[f] = s;
    shiftv[f] = beta[f] - mean * s;
}

// ---------------------------------------------------------------------------
// Layer-2 MLP fused with the final linear head (C=10); BN affine on the fly.
// ---------------------------------------------------------------------------
__global__ __launch_bounds__(64)
void mlp2_kernel(const float* __restrict__ h1p, const float* __restrict__ scale,
                 const float* __restrict__ shiftv, const float* __restrict__ agg,
                 const float* __restrict__ W2a, const float* __restrict__ B2a,
                 const float* __restrict__ W2b, const float* __restrict__ B2b,
                 const float* __restrict__ LW, const float* __restrict__ LB,
                 float* __restrict__ out, int N) {
    int i = blockIdx.x * blockDim.x + threadIdx.x;
    if (i >= N) return;
    long long base = (long long)i * H;
    float h[H], u[H];
#pragma unroll
    for (int f = 0; f < H; ++f)
        h[f] = (h1p[base + f] * scale[f] + shiftv[f]) + agg[base + f];
#pragma unroll
    for (int j = 0; j < H; ++j) u[j] = B2a[j];
#pragma unroll
    for (int k = 0; k < H; ++k) {
        float hk = h[k];
#pragma unroll
        for (int j = 0; j < H; ++j) u[j] = fmaf(hk, W2a[k * H + j], u[j]);
    }
#pragma unroll
    for (int j = 0; j < H; ++j) u[j] = fmaxf(u[j], 0.f);
#pragma unroll
    for (int j = 0; j < H; ++j) h[j] = B2b[j];
#pragma unroll
    for (int k = 0; k < H; ++k) {
        float uk = u[k];
#pragma unroll
        for (int j = 0; j < H; ++j) h[j] = fmaf(uk, W2b[k * H + j], h[j]);
    }
#pragma unroll
    for (int c = 0; c < 10; ++c) {
        float acc = LB[c];
#pragma unroll
        for (int k = 0; k < H; ++k) acc = fmaf(h[k], LW[k * 10 + c], acc);
        out[(long long)i * 10 + c] = acc;
    }
}

extern "C" void kernel_launch(void* const* d_in, const int* in_sizes, int n_in,
                              void* d_out, int out_size, void* d_ws, size_t ws_size,
                              hipStream_t stream) {
    const float* x    = (const float*)d_in[0];
    const int*   ei   = (const int*)d_in[1];
    const float* w1a  = (const float*)d_in[2];
    const float* b1a  = (const float*)d_in[3];
    const float* w1b  = (const float*)d_in[4];
    const float* b1b  = (const float*)d_in[5];
    const float* bng  = (const float*)d_in[6];
    const float* bnb  = (const float*)d_in[7];
    const float* w2a  = (const float*)d_in[8];
    const float* b2a  = (const float*)d_in[9];
    const float* w2b  = (const float*)d_in[10];
    const float* b2b  = (const float*)d_in[11];
    const float* linw = (const float*)d_in[12];
    const float* linb = (const float*)d_in[13];

    int N = in_sizes[0] / H;       // 100000
    int E = in_sizes[1] / 2;       // 1600000

    float* ws    = (float*)d_ws;
    float* agg   = ws;                               // N*H fp32 (reused for both layers)
    float* h1p   = ws + (size_t)N * H;               // N*H fp32, pre-BN h1
    float* stats = ws + 2 * (size_t)N * H;           // 128: colsum + colsumsq
    float* scale = stats + 128;                      // 64
    float* shiftv= stats + 192;                      // 64

    hipMemsetAsync(agg, 0, (size_t)N * H * sizeof(float), stream);
    hipMemsetAsync(stats, 0, 128 * sizeof(float), stream);

    long long tot = (long long)E * (H / 4);
    int sblocks = (int)((tot + 255) / 256);
    scatter1_kernel<<<sblocks, 256, 0, stream>>>(x, ei, agg, E, N);
    mlp1_kernel<<<(N + 63) / 64, 64, 0, stream>>>(x, agg, w1a, b1a, w1b, b1b, h1p, N);
    colsum_kernel<<<512, 256, 0, stream>>>(h1p, stats, N);
    bn_finalize_kernel<<<1, 64, 0, stream>>>(stats, bng, bnb, scale, shiftv, (float)N);

    hipMemsetAsync(agg, 0, (size_t)N * H * sizeof(float), stream);
    scatter2_kernel<<<sblocks, 256, 0, stream>>>(h1p, scale, shiftv, ei, agg, E, N);
    mlp2_kernel<<<(N + 63) / 64, 64, 0, stream>>>(h1p, scale, shiftv, agg,
                                                  w2a, b2a, w2b, b2b, linw, linb,
                                                  (float*)d_out, N);
}

// Round 3
// 619.265 us; speedup vs baseline: 5.0154x; 5.0154x over previous
//
#include <hip/hip_runtime.h>

#define H 64
#define SCAN_CH 1024   // elements per scan block (256 threads x 4)

// ---------------------------------------------------------------------------
// CSR build: histogram of in-degrees
// ---------------------------------------------------------------------------
__global__ void hist_kernel(const int* __restrict__ ei, int* __restrict__ deg, int E, int N) {
    int e = blockIdx.x * blockDim.x + threadIdx.x;
    if (e >= E) return;
    int d = ei[E + e];
    if ((unsigned)d < (unsigned)N) atomicAdd(&deg[d], 1);
}

// 3-phase exclusive scan of deg[0..N) -> rowptr[0..N], plus cursor copy.
__global__ void scan1_kernel(const int* __restrict__ deg, int* __restrict__ psum, int N) {
    __shared__ int sd[256];
    int t = threadIdx.x;
    int base = blockIdx.x * SCAN_CH + t * 4;
    int s = 0;
#pragma unroll
    for (int k = 0; k < 4; ++k) { int idx = base + k; if (idx < N) s += deg[idx]; }
    sd[t] = s; __syncthreads();
    for (int off = 128; off > 0; off >>= 1) {
        if (t < off) sd[t] += sd[t + off];
        __syncthreads();
    }
    if (t == 0) psum[blockIdx.x] = sd[0];
}

__global__ void scan2_kernel(int* __restrict__ psum, int B) {
    __shared__ int sd[256];
    int t = threadIdx.x;
    int v = (t < B) ? psum[t] : 0;
    sd[t] = v; __syncthreads();
    for (int off = 1; off < 256; off <<= 1) {
        int add = (t >= off) ? sd[t - off] : 0;
        __syncthreads();
        sd[t] += add;
        __syncthreads();
    }
    if (t < B) psum[t] = sd[t] - v;   // exclusive
}

__global__ void scan3_kernel(const int* __restrict__ deg, const int* __restrict__ psum,
                             int* __restrict__ rowptr, int* __restrict__ cursor, int N, int E) {
    __shared__ int sd[256];
    int t = threadIdx.x;
    int base = blockIdx.x * SCAN_CH + t * 4;
    int v[4]; int s = 0;
#pragma unroll
    for (int k = 0; k < 4; ++k) { int idx = base + k; v[k] = (idx < N) ? deg[idx] : 0; s += v[k]; }
    sd[t] = s; __syncthreads();
    int mine = s;
    for (int off = 1; off < 256; off <<= 1) {
        int add = (t >= off) ? sd[t - off] : 0;
        __syncthreads();
        sd[t] += add;
        __syncthreads();
    }
    int run = sd[t] - mine + psum[blockIdx.x];
#pragma unroll
    for (int k = 0; k < 4; ++k) {
        int idx = base + k;
        if (idx < N) {
            rowptr[idx] = run; cursor[idx] = run;
            run += v[k];
            if (idx == N - 1) rowptr[N] = run;   // == E
        }
    }
}

// Bucket-fill: ebuf[cursor[dst]++] = src
__global__ void fill_kernel(const int* __restrict__ ei, int* __restrict__ cursor,
                            int* __restrict__ ebuf, int E, int N) {
    int e = blockIdx.x * blockDim.x + threadIdx.x;
    if (e >= E) return;
    int s = ei[e];
    int d = ei[E + e];
    if ((unsigned)s >= (unsigned)N || (unsigned)d >= (unsigned)N) return;
    int p = atomicAdd(&cursor[d], 1);
    ebuf[p] = s;
}

// ---------------------------------------------------------------------------
// Layer-1 gather: one wave per node, lane = feature.
// bufA[i] = x[i] + sum_{j->i} x[j]   (no atomics; x rows are LLC-resident)
// ---------------------------------------------------------------------------
__global__ __launch_bounds__(256)
void gather1_kernel(const float* __restrict__ x, const int* __restrict__ rowptr,
                    const int* __restrict__ ebuf, float* __restrict__ bufA, int N) {
    int wid = (int)(((long long)blockIdx.x * blockDim.x + threadIdx.x) >> 6);
    int lane = threadIdx.x & 63;
    if (wid >= N) return;
    int p = rowptr[wid], pe = rowptr[wid + 1];
    float acc = x[(long long)wid * H + lane];
    for (; p + 4 <= pe; p += 4) {
        int s0 = ebuf[p], s1 = ebuf[p + 1], s2 = ebuf[p + 2], s3 = ebuf[p + 3];
        float a0 = x[(long long)s0 * H + lane];
        float a1 = x[(long long)s1 * H + lane];
        float a2 = x[(long long)s2 * H + lane];
        float a3 = x[(long long)s3 * H + lane];
        acc += (a0 + a1) + (a2 + a3);
    }
    for (; p < pe; ++p) acc += x[(long long)ebuf[p] * H + lane];
    bufA[(long long)wid * H + lane] = acc;
}

// ---------------------------------------------------------------------------
// Layer-2 gather with folded BN affine: sum_j BN(h1_j) = s*sum_j h1_j + deg*t
// ---------------------------------------------------------------------------
__global__ __launch_bounds__(256)
void gather2_kernel(const float* __restrict__ h1p, const float* __restrict__ scale,
                    const float* __restrict__ shiftv, const int* __restrict__ rowptr,
                    const int* __restrict__ ebuf, float* __restrict__ bufB, int N) {
    int wid = (int)(((long long)blockIdx.x * blockDim.x + threadIdx.x) >> 6);
    int lane = threadIdx.x & 63;
    if (wid >= N) return;
    int p0 = rowptr[wid], pe = rowptr[wid + 1];
    int p = p0;
    float acc = 0.f;
    for (; p + 4 <= pe; p += 4) {
        int s0 = ebuf[p], s1 = ebuf[p + 1], s2 = ebuf[p + 2], s3 = ebuf[p + 3];
        float a0 = h1p[(long long)s0 * H + lane];
        float a1 = h1p[(long long)s1 * H + lane];
        float a2 = h1p[(long long)s2 * H + lane];
        float a3 = h1p[(long long)s3 * H + lane];
        acc += (a0 + a1) + (a2 + a3);
    }
    for (; p < pe; ++p) acc += h1p[(long long)ebuf[p] * H + lane];
    float deg = (float)(pe - p0);
    bufB[(long long)wid * H + lane] = acc * scale[lane] + deg * shiftv[lane];
}

// ---------------------------------------------------------------------------
// Thread-per-node 2-layer MLP (layer 1), IN PLACE on hbuf (each thread owns
// its row: reads row -> computes -> writes same row; no cross-thread aliasing).
// ---------------------------------------------------------------------------
__global__ __launch_bounds__(64)
void mlp1_kernel(float* hbuf,
                 const float* __restrict__ W1a, const float* __restrict__ B1a,
                 const float* __restrict__ W1b, const float* __restrict__ B1b,
                 int N) {
    int i = blockIdx.x * blockDim.x + threadIdx.x;
    if (i >= N) return;
    long long base = (long long)i * H;
    float h[H], u[H];
#pragma unroll
    for (int f = 0; f < H; ++f) h[f] = hbuf[base + f];
#pragma unroll
    for (int j = 0; j < H; ++j) u[j] = B1a[j];
#pragma unroll
    for (int k = 0; k < H; ++k) {
        float hk = h[k];
#pragma unroll
        for (int j = 0; j < H; ++j) u[j] = fmaf(hk, W1a[k * H + j], u[j]);
    }
#pragma unroll
    for (int j = 0; j < H; ++j) u[j] = fmaxf(u[j], 0.f);
#pragma unroll
    for (int j = 0; j < H; ++j) h[j] = B1b[j];
#pragma unroll
    for (int k = 0; k < H; ++k) {
        float uk = u[k];
#pragma unroll
        for (int j = 0; j < H; ++j) h[j] = fmaf(uk, W1b[k * H + j], h[j]);
    }
#pragma unroll
    for (int j = 0; j < H; ++j) hbuf[base + j] = h[j];
}

// Column sums + sumsq of h1p for batchnorm stats.
__global__ void colsum_kernel(const float* __restrict__ h1p, float* __restrict__ stats, int N) {
    int lane = threadIdx.x & 63;
    int wave = (int)((blockIdx.x * (long long)blockDim.x + threadIdx.x) >> 6);
    int nwaves = (int)(((long long)gridDim.x * blockDim.x) >> 6);
    float s = 0.f, s2 = 0.f;
    for (int r = wave; r < N; r += nwaves) {
        float v = h1p[(long long)r * H + lane];
        s += v;
        s2 += v * v;
    }
    unsafeAtomicAdd(&stats[lane], s);
    unsafeAtomicAdd(&stats[H + lane], s2);
}

__global__ void bn_finalize_kernel(const float* __restrict__ stats,
                                   const float* __restrict__ gamma,
                                   const float* __restrict__ beta,
                                   float* __restrict__ scale, float* __restrict__ shiftv, float n) {
    int f = threadIdx.x;
    if (f >= H) return;
    float mean = stats[f] / n;
    float var = stats[H + f] / n - mean * mean;   // biased, matches jnp.var
    var = fmaxf(var, 0.f);
    float s = gamma[f] * rsqrtf(var + 1e-5f);
    scale[f] = s;
    shiftv[f] = beta[f] - mean * s;
}

// Layer-2 MLP fused with final linear head (C=10); BN affine for self term.
__global__ __launch_bounds__(64)
void mlp2_kernel(const float* __restrict__ h1p, const float* __restrict__ scale,
                 const float* __restrict__ shiftv, const float* __restrict__ agg,
                 const float* __restrict__ W2a, const float* __restrict__ B2a,
                 const float* __restrict__ W2b, const float* __restrict__ B2b,
                 const float* __restrict__ LW, const float* __restrict__ LB,
                 float* __restrict__ out, int N) {
    int i = blockIdx.x * blockDim.x + threadIdx.x;
    if (i >= N) return;
    long long base = (long long)i * H;
    float h[H], u[H];
#pragma unroll
    for (int f = 0; f < H; ++f)
        h[f] = (h1p[base + f] * scale[f] + shiftv[f]) + agg[base + f];
#pragma unroll
    for (int j = 0; j < H; ++j) u[j] = B2a[j];
#pragma unroll
    for (int k = 0; k < H; ++k) {
        float hk = h[k];
#pragma unroll
        for (int j = 0; j < H; ++j) u[j] = fmaf(hk, W2a[k * H + j], u[j]);
    }
#pragma unroll
    for (int j = 0; j < H; ++j) u[j] = fmaxf(u[j], 0.f);
#pragma unroll
    for (int j = 0; j < H; ++j) h[j] = B2b[j];
#pragma unroll
    for (int k = 0; k < H; ++k) {
        float uk = u[k];
#pragma unroll
        for (int j = 0; j < H; ++j) h[j] = fmaf(uk, W2b[k * H + j], h[j]);
    }
#pragma unroll
    for (int c = 0; c < 10; ++c) {
        float acc = LB[c];
#pragma unroll
        for (int k = 0; k < H; ++k) acc = fmaf(h[k], LW[k * 10 + c], acc);
        out[(long long)i * 10 + c] = acc;
    }
}

extern "C" void kernel_launch(void* const* d_in, const int* in_sizes, int n_in,
                              void* d_out, int out_size, void* d_ws, size_t ws_size,
                              hipStream_t stream) {
    const float* x    = (const float*)d_in[0];
    const int*   ei   = (const int*)d_in[1];
    const float* w1a  = (const float*)d_in[2];
    const float* b1a  = (const float*)d_in[3];
    const float* w1b  = (const float*)d_in[4];
    const float* b1b  = (const float*)d_in[5];
    const float* bng  = (const float*)d_in[6];
    const float* bnb  = (const float*)d_in[7];
    const float* w2a  = (const float*)d_in[8];
    const float* b2a  = (const float*)d_in[9];
    const float* w2b  = (const float*)d_in[10];
    const float* b2b  = (const float*)d_in[11];
    const float* linw = (const float*)d_in[12];
    const float* linb = (const float*)d_in[13];

    int N = in_sizes[0] / H;       // 100000
    int E = in_sizes[1] / 2;       // 1600000

    // ---- workspace layout ----
    float* ws     = (float*)d_ws;
    float* bufA   = ws;                          // N*H: h_in1, then h1p in place
    float* bufB   = ws + (size_t)N * H;          // N*H: layer-2 aggregate
    float* stats  = ws + 2 * (size_t)N * H;      // 128 (colsum+sumsq)
    float* scale  = stats + 128;                 // 64
    float* shiftv = stats + 192;                 // 64
    int*   deg    = (int*)(stats + 256);         // N
    int*   rowptr = deg + N;                     // N+1
    int*   cursor = rowptr + (N + 1);            // N
    int*   psum   = cursor + N;                  // <=256
    int*   ebuf   = psum + 256;                  // E

    int B = (N + SCAN_CH - 1) / SCAN_CH;         // scan blocks (98 for N=100k)

    hipMemsetAsync(deg, 0, (size_t)N * sizeof(int), stream);
    hipMemsetAsync(stats, 0, 128 * sizeof(float), stream);

    // CSR build (once; serves both layers)
    hist_kernel<<<(E + 255) / 256, 256, 0, stream>>>(ei, deg, E, N);
    scan1_kernel<<<B, 256, 0, stream>>>(deg, psum, N);
    scan2_kernel<<<1, 256, 0, stream>>>(psum, B);
    scan3_kernel<<<B, 256, 0, stream>>>(deg, psum, rowptr, cursor, N, E);
    fill_kernel<<<(E + 255) / 256, 256, 0, stream>>>(ei, cursor, ebuf, E, N);

    int gblocks = (int)(((long long)N * 64 + 255) / 256);
    gather1_kernel<<<gblocks, 256, 0, stream>>>(x, rowptr, ebuf, bufA, N);
    mlp1_kernel<<<(N + 63) / 64, 64, 0, stream>>>(bufA, w1a, b1a, w1b, b1b, N);
    colsum_kernel<<<512, 256, 0, stream>>>(bufA, stats, N);
    bn_finalize_kernel<<<1, 64, 0, stream>>>(stats, bng, bnb, scale, shiftv, (float)N);

    gather2_kernel<<<gblocks, 256, 0, stream>>>(bufA, scale, shiftv, rowptr, ebuf, bufB, N);
    mlp2_kernel<<<(N + 63) / 64, 64, 0, stream>>>(bufA, scale, shiftv, bufB,
                                                  w2a, b2a, w2b, b2b, linw, linb,
                                                  (float*)d_out, N);
}